// Round 6
// baseline (4764.935 us; speedup 1.0000x reference)
//
#include <hip/hip_runtime.h>

typedef unsigned short u16;
typedef unsigned int u32;
typedef unsigned long long u64;
typedef __attribute__((ext_vector_type(8))) short bf16x8;
typedef __attribute__((ext_vector_type(4))) float f32x4;
typedef __attribute__((ext_vector_type(8))) unsigned short u16x8;
typedef __attribute__((ext_vector_type(4))) unsigned short u16x4;

#define MFMA16(a, b, c) __builtin_amdgcn_mfma_f32_16x16x32_bf16(a, b, c, 0, 0, 0)

__device__ __forceinline__ u16 f2b(float f) {
    u32 u = __builtin_bit_cast(u32, f);
    u32 r = (u + 0x7fffu + ((u >> 16) & 1u)) >> 16;
    return (u16)r;
}
__device__ __forceinline__ float b2f(u16 h) {
    u32 u = ((u32)h) << 16;
    return __builtin_bit_cast(float, u);
}
__device__ __forceinline__ float sigm(float x) { return 1.0f / (1.0f + __expf(-x)); }
__device__ __forceinline__ float tanh_fast(float x) { return 1.0f - 2.0f / (__expf(2.0f * x) + 1.0f); }

// Cross-XCD-coherent accesses WITHOUT fences: agent-scope relaxed atomics
// lower to sc1 (MALL-coherent) global accesses. No release/acquire anywhere:
// sc1 stores complete at the MALL (the serialization point) before a
// wave-level s_waitcnt vmcnt(0) retires, so a later relaxed flag store is
// observed strictly after them. Avoids buffer_wbl2/buffer_inv entirely.
__device__ __forceinline__ u64 aload64(const void* p) {
    return __hip_atomic_load((const u64*)p, __ATOMIC_RELAXED, __HIP_MEMORY_SCOPE_AGENT);
}
__device__ __forceinline__ u32 aload32(const void* p) {
    return __hip_atomic_load((const u32*)p, __ATOMIC_RELAXED, __HIP_MEMORY_SCOPE_AGENT);
}
__device__ __forceinline__ void astore32(void* p, u32 v) {
    __hip_atomic_store((u32*)p, v, __ATOMIC_RELAXED, __HIP_MEMORY_SCOPE_AGENT);
}
// wave-level drain of this wave's outstanding vmem (stores -> MALL acks)
__device__ __forceinline__ void wait_vm0() {
    asm volatile("s_waitcnt vmcnt(0)" ::: "memory");
}

// ---------------------------------------------------------------------------
// Embedding gather + f32->bf16 cast, time-major output x[t*64+b][e]
__global__ __launch_bounds__(256) void embed_k(const int* __restrict__ enc,
                                               const float* __restrict__ emb,
                                               u16* __restrict__ xb) {
    int idx = (blockIdx.x * 256 + threadIdx.x) * 4;
    int row = idx >> 9;
    int e = idx & 511;
    int t = row >> 6, b = row & 63;
    int tok = enc[b * 256 + t];
    const float4 v = *(const float4*)(emb + (size_t)tok * 512 + e);
    u16x4 o;
    o.x = f2b(v.x); o.y = f2b(v.y); o.z = f2b(v.z); o.w = f2b(v.w);
    *(u16x4*)(xb + idx) = o;
}

// Mask words: maskw[t] bit b = (enc[b][t] != 0)
__global__ void mask_k(const int* __restrict__ enc, u64* __restrict__ mw) {
    int t = threadIdx.x;
    u64 m = 0;
#pragma unroll 8
    for (int b = 0; b < 64; ++b)
        if (enc[b * 256 + t] != 0) m |= (1ull << b);
    mw[t] = m;
}

// ---------------------------------------------------------------------------
// Cast f32 [K][N] -> bf16 transposed [N][K] via LDS tile
__global__ __launch_bounds__(256) void castT_k(const float* __restrict__ src,
                                               u16* __restrict__ dst, int K, int N) {
    __shared__ float tile[64][65];
    int n0 = blockIdx.x * 64, k0 = blockIdx.y * 64;
    int tid = threadIdx.x;
#pragma unroll
    for (int it = 0; it < 4; ++it) {
        int e = tid + it * 256;
        int kk = e >> 4;
        int nn = (e & 15) * 4;
        const float4 v = *(const float4*)(src + (size_t)(k0 + kk) * N + n0 + nn);
        tile[kk][nn] = v.x; tile[kk][nn + 1] = v.y;
        tile[kk][nn + 2] = v.z; tile[kk][nn + 3] = v.w;
    }
    __syncthreads();
#pragma unroll
    for (int it = 0; it < 2; ++it) {
        int e = tid + it * 256;
        int nn = e >> 3;
        int ks = (e & 7) * 8;
        u16x8 o;
#pragma unroll
        for (int j = 0; j < 8; ++j) o[j] = f2b(tile[ks + j][nn]);
        *(u16x8*)(dst + (size_t)(n0 + nn) * K + k0 + ks) = o;
    }
}

// ---------------------------------------------------------------------------
// bf16 MFMA GEMM: zxT[dir][t][col][b] = (A[16384][Ak] @ Bt[dir]^T + bias[dir]),
// output TRANSPOSED per timestep for the recurrence's vectorized reads.
__global__ __launch_bounds__(256) void gemm_bias_k(
    const u16* __restrict__ A, int Ak,
    const u16* __restrict__ BtF, const u16* __restrict__ BtB,
    const float* __restrict__ biasF, const float* __restrict__ biasB,
    u16* __restrict__ outF, u16* __restrict__ outB) {
    const int dir = blockIdx.z;
    const u16* __restrict__ Bt = dir ? BtB : BtF;
    const float* __restrict__ bias = dir ? biasB : biasF;
    u16* __restrict__ out = dir ? outB : outF;

    const int m0 = blockIdx.y * 128, n0 = blockIdx.x * 128;
    __shared__ __align__(16) u16 As[128 * 40];
    __shared__ __align__(16) u16 Bs[128 * 40];
    const int tid = threadIdx.x;
    const int lane = tid & 63, w = tid >> 6;
    const int l15 = lane & 15, quad = lane >> 4;
    const int rb = (w >> 1) * 64, cb = (w & 1) * 64;

    f32x4 acc[4][4];
#pragma unroll
    for (int i = 0; i < 4; ++i)
#pragma unroll
        for (int j = 0; j < 4; ++j) acc[i][j] = (f32x4){0.f, 0.f, 0.f, 0.f};

    const int nkt = Ak >> 5;
    for (int kt = 0; kt < nkt; ++kt) {
        __syncthreads();
#pragma unroll
        for (int it = 0; it < 2; ++it) {
            int s = tid + it * 256;
            int r = s >> 2, seg = s & 3;
            *(uint4*)&As[r * 40 + seg * 8] =
                *(const uint4*)&A[(size_t)(m0 + r) * Ak + kt * 32 + seg * 8];
            *(uint4*)&Bs[r * 40 + seg * 8] =
                *(const uint4*)&Bt[(size_t)(n0 + r) * Ak + kt * 32 + seg * 8];
        }
        __syncthreads();
        bf16x8 af[4], bfr[4];
#pragma unroll
        for (int i = 0; i < 4; ++i)
            af[i] = *(const bf16x8*)&As[(rb + i * 16 + l15) * 40 + quad * 8];
#pragma unroll
        for (int j = 0; j < 4; ++j)
            bfr[j] = *(const bf16x8*)&Bs[(cb + j * 16 + l15) * 40 + quad * 8];
#pragma unroll
        for (int i = 0; i < 4; ++i)
#pragma unroll
            for (int j = 0; j < 4; ++j) acc[i][j] = MFMA16(af[i], bfr[j], acc[i][j]);
    }
    // epilogue: add bias, store bf16 transposed: zxT[(t*2048 + col)*64 + b]
    // rows m..m+3 share t because m === 0 (mod 4) and 64 | t-boundary.
#pragma unroll
    for (int j = 0; j < 4; ++j) {
        int col = n0 + cb + j * 16 + l15;
        float bv = bias[col];
#pragma unroll
        for (int i = 0; i < 4; ++i) {
            int m = m0 + rb + i * 16 + quad * 4;
            int t = m >> 6, b0 = m & 63;
            u16x4 o;
#pragma unroll
            for (int r = 0; r < 4; ++r) o[r] = f2b(acc[i][j][r] + bv);
            *(u16x4*)&out[((size_t)t * 2048 + col) * 64 + b0] = o;
        }
    }
}

// ---------------------------------------------------------------------------
// Persistent bidirectional LSTM recurrence, fence-free + barrier-free.
// 64 WGs: 0..31 fwd, 32..63 bwd. Each WG owns 16 units (64 gate-cols, 4
// N-tiles) with U-slices resident in registers. h exchange via agent-scope
// relaxed atomics (sc1 -> MALL, coherent across XCDs).
// PER-WAVE dataflow sync: producer wave w writes batch rows w*16..w*16+15;
// consumer wave w reads exactly those rows -> wave w only needs wave-w flags
// of the 32 WGs. Each wave: store h rows -> s_waitcnt vmcnt(0) -> publish
// own flag -> (out stores + zx prefetch overlap the next gate). NO
// __syncthreads in the loop; waves fully decoupled.
__global__ __launch_bounds__(256, 1) void lstm_rec_k(
    const u16* __restrict__ zxF, const u16* __restrict__ zxB,  // [256][2048][64]
    const u16* __restrict__ UtF, const u16* __restrict__ UtB,  // [2048][512]
    const u64* __restrict__ maskw,
    u16* __restrict__ hbufF, u16* __restrict__ hbufB,          // each 2*[64*512]
    u32* __restrict__ flgF, u32* __restrict__ flgB,            // each [4][32]
    u16* __restrict__ out1,    // layer 1: [256][64][1024] bf16
    float* __restrict__ out2,  // layer 2: d_out
    int layer) {
    const int wg = blockIdx.x;
    const int dir = wg >> 5;
    const int wgu = wg & 31;
    const u16* __restrict__ zx = dir ? zxB : zxF;
    const u16* __restrict__ Ut = dir ? UtB : UtF;
    u16* __restrict__ hbuf = dir ? hbufB : hbufF;
    u32* __restrict__ flg = dir ? flgB : flgF;

    const int tid = threadIdx.x;
    const int lane = tid & 63, w = tid >> 6;
    const int l15 = lane & 15, quad = lane >> 4;
    const bool hi = (lane & 8) != 0;
    const int j7 = lane & 7;
    // gate-col per N-tile nt (0,1 = i/f unit-halves; 2,3 = g/o unit-halves)
    int gcl[4];
#pragma unroll
    for (int nt = 0; nt < 4; ++nt)
        gcl[nt] = (l15 >> 3) * 512 + (nt >> 1) * 1024 + wgu * 16 + (nt & 1) * 8 + j7;
    const int u_a = wgu * 16 + j7;  // unit for ug=0; ug=1 is u_a+8
    const int brow = w * 16 + l15;
    const int b0 = w * 16 + quad * 4;  // batch base for acc rows
    u32* __restrict__ myflag = &flg[w * 32 + wgu];
    const u32* __restrict__ pollflag = &flg[w * 32 + (lane & 31)];

    // Preload U fragments: 4 N-tiles x 16 K-chunks (unified VGPR/AGPR file)
    bf16x8 bfr[4][16];
#pragma unroll
    for (int nt = 0; nt < 4; ++nt)
#pragma unroll
        for (int kt = 0; kt < 16; ++kt)
            bfr[nt][kt] = *(const bf16x8*)&Ut[(size_t)gcl[nt] * 512 + kt * 32 + quad * 8];

    float hreg[2][4] = {{0.f, 0.f, 0.f, 0.f}, {0.f, 0.f, 0.f, 0.f}};
    float creg[2][4] = {{0.f, 0.f, 0.f, 0.f}, {0.f, 0.f, 0.f, 0.f}};

    // initial zx prefetch (t of step 0)
    int t0 = dir ? 255 : 0;
    u16x4 pz[4];
#pragma unroll
    for (int nt = 0; nt < 4; ++nt)
        pz[nt] = *(const u16x4*)&zx[((size_t)t0 * 2048 + gcl[nt]) * 64 + b0];

    union HU { u64 q[2]; bf16x8 v; };

    for (int s = 0; s < 256; ++s) {
        const int t = dir ? (255 - s) : s;

        // gate: wait until wave-w of all 32 WGs published step s
        // (flag==s means they finished step s-1 incl. their h[s-1] reads).
        if (s) {
            u32 v = aload32(pollflag);
            while (__ballot(v < (u32)s)) v = aload32(pollflag);
            asm volatile("" ::: "memory");  // keep h loads below the gate
        }

        // h[s] slot: sc1 loads from MALL (rows w*16..w*16+15)
        const u16* hbase = hbuf + (s & 1) * 32768 + brow * 512 + quad * 8;
        bf16x8 hfr[16];
#pragma unroll
        for (int kt = 0; kt < 16; ++kt) {
            HU hu;
            hu.q[0] = aload64(hbase + kt * 32);
            hu.q[1] = aload64(hbase + kt * 32 + 4);
            hfr[kt] = hu.v;
        }

        f32x4 acc[4];
#pragma unroll
        for (int nt = 0; nt < 4; ++nt)
#pragma unroll
            for (int r = 0; r < 4; ++r) acc[nt][r] = b2f(pz[nt][r]);
#pragma unroll
        for (int kt = 0; kt < 16; ++kt)
#pragma unroll
            for (int nt = 0; nt < 4; ++nt)
                acc[nt] = MFMA16(hfr[kt], bfr[nt][kt], acc[nt]);

        const u64 mw = maskw[t];
        u16* __restrict__ hn = hbuf + ((s + 1) & 1) * 32768;
        u32 pairs[2][4];
#pragma unroll
        for (int r = 0; r < 4; ++r) {
            int b = b0 + r;
            bool msk = (mw >> b) & 1ull;
#pragma unroll
            for (int ug = 0; ug < 2; ++ug) {
                float z0 = acc[ug][r], z1 = acc[2 + ug][r];
                float p0 = __shfl_xor(z0, 8);
                float p1 = __shfl_xor(z1, 8);
                float iz = hi ? p0 : z0, fz = hi ? z0 : p0;
                float gz = hi ? p1 : z1, oz = hi ? z1 : p1;
                float i_ = sigm(iz), f_ = sigm(fz), g_ = tanh_fast(gz), o_ = sigm(oz);
                float cn = f_ * creg[ug][r] + i_ * g_;
                float hv = o_ * tanh_fast(cn);
                if (!msk) { cn = creg[ug][r]; hv = hreg[ug][r]; }
                creg[ug][r] = cn; hreg[ug][r] = hv;
                if (!hi) {
                    u16 hb = f2b(hv);
                    // pack (u, u+1) into u32; even lane stores (u_a even there)
                    u32 pair = (u32)hb | (((u32)(u16)__shfl_xor((int)(u32)hb, 1)) << 16);
                    pairs[ug][r] = pair;
                    if (!(lane & 1)) astore32(&hn[b * 512 + u_a + ug * 8], pair);
                }
            }
        }

        // drain THIS WAVE's h stores to the MALL, then publish wave flag
        wait_vm0();
        if (lane == 0) astore32(myflag, (u32)(s + 1));

        // post-publish (overlaps the next gate): zx prefetch + out stores
        {
            int tn = dir ? (s < 255 ? 254 - s : 0) : (s < 255 ? s + 1 : 255);
#pragma unroll
            for (int nt = 0; nt < 4; ++nt)
                pz[nt] = *(const u16x4*)&zx[((size_t)tn * 2048 + gcl[nt]) * 64 + b0];
        }
        if (!hi) {
#pragma unroll
            for (int r = 0; r < 4; ++r) {
                int b = b0 + r;
                if (layer == 1) {
                    if (!(lane & 1)) {
#pragma unroll
                        for (int ug = 0; ug < 2; ++ug)
                            astore32(&out1[((size_t)t * 64 + b) * 1024 + dir * 512 + u_a + ug * 8],
                                     pairs[ug][r]);
                    }
                } else {
#pragma unroll
                    for (int ug = 0; ug < 2; ++ug)
                        astore32(&out2[(size_t)b * 262144 + (size_t)t * 1024 + dir * 512 + u_a + ug * 8],
                                 __builtin_bit_cast(u32, hreg[ug][r]));
                }
            }
        }
        if (layer == 2 && s == 255 && !hi) {
#pragma unroll
            for (int r = 0; r < 4; ++r) {
                int b = b0 + r;
#pragma unroll
                for (int ug = 0; ug < 2; ++ug) {
                    astore32(&out2[16777216 + b * 1024 + dir * 512 + u_a + ug * 8],
                             __builtin_bit_cast(u32, hreg[ug][r]));
                    astore32(&out2[16777216 + 65536 + b * 1024 + dir * 512 + u_a + ug * 8],
                             __builtin_bit_cast(u32, creg[ug][r]));
                }
            }
        }
    }
}

// ---------------------------------------------------------------------------
extern "C" void kernel_launch(void* const* d_in, const int* in_sizes, int n_in,
                              void* d_out, int out_size, void* d_ws, size_t ws_size,
                              hipStream_t stream) {
    const int* enc = (const int*)d_in[0];
    const float* emb = (const float*)d_in[1];
    const float* W1f = (const float*)d_in[2];
    const float* U1f = (const float*)d_in[3];
    const float* b1f = (const float*)d_in[4];
    const float* W1b = (const float*)d_in[5];
    const float* U1b = (const float*)d_in[6];
    const float* b1b = (const float*)d_in[7];
    const float* W2f = (const float*)d_in[8];
    const float* U2f = (const float*)d_in[9];
    const float* b2f = (const float*)d_in[10];
    const float* W2b = (const float*)d_in[11];
    const float* U2b = (const float*)d_in[12];
    const float* b2b = (const float*)d_in[13];

    char* ws = (char*)d_ws;
    constexpr size_t ZXF = 0;                      // 67,108,864  bf16 [256][2048][64]
    constexpr size_t ZXB = 67108864;               // 67,108,864
    constexpr size_t XB = 134217728;               // 16,777,216  bf16 [16384][512]
    constexpr size_t OUT1 = 150994944;             // 33,554,432  bf16 [16384][1024]
    constexpr size_t WT = 184549376;               // 20,971,520 packed bf16 transposed weights
    constexpr size_t W1FT = WT + 0;
    constexpr size_t W1BT = WT + 2097152;
    constexpr size_t U1FT = WT + 4194304;
    constexpr size_t U1BT = WT + 6291456;
    constexpr size_t W2FT = WT + 8388608;
    constexpr size_t W2BT = WT + 12582912;
    constexpr size_t U2FT = WT + 16777216;
    constexpr size_t U2BT = WT + 18874368;
    constexpr size_t HBUF = 205520896;             // 524,288: [layer][dir][2][64*512] bf16
    constexpr size_t FLG = HBUF + 524288;          // 4 x 128 u32 = 2048 B
    constexpr size_t MASKW = FLG + 2048;           // 2048 bytes

    u16* zxF = (u16*)(ws + ZXF);
    u16* zxB = (u16*)(ws + ZXB);
    u16* xb = (u16*)(ws + XB);
    u16* out1 = (u16*)(ws + OUT1);
    u32* flgs = (u32*)(ws + FLG);
    u64* maskw = (u64*)(ws + MASKW);

    // zero h init buffers + flags (ws is poisoned 0xAA each launch)
    hipMemsetAsync(ws + HBUF, 0, 524288 + 2048, stream);

    embed_k<<<8192, 256, 0, stream>>>(enc, emb, xb);
    mask_k<<<1, 256, 0, stream>>>(enc, maskw);

    castT_k<<<dim3(32, 8), 256, 0, stream>>>(W1f, (u16*)(ws + W1FT), 512, 2048);
    castT_k<<<dim3(32, 8), 256, 0, stream>>>(W1b, (u16*)(ws + W1BT), 512, 2048);
    castT_k<<<dim3(32, 8), 256, 0, stream>>>(U1f, (u16*)(ws + U1FT), 512, 2048);
    castT_k<<<dim3(32, 8), 256, 0, stream>>>(U1b, (u16*)(ws + U1BT), 512, 2048);
    castT_k<<<dim3(32, 16), 256, 0, stream>>>(W2f, (u16*)(ws + W2FT), 1024, 2048);
    castT_k<<<dim3(32, 16), 256, 0, stream>>>(W2b, (u16*)(ws + W2BT), 1024, 2048);
    castT_k<<<dim3(32, 8), 256, 0, stream>>>(U2f, (u16*)(ws + U2FT), 512, 2048);
    castT_k<<<dim3(32, 8), 256, 0, stream>>>(U2b, (u16*)(ws + U2BT), 512, 2048);

    gemm_bias_k<<<dim3(16, 128, 2), 256, 0, stream>>>(
        xb, 512, (u16*)(ws + W1FT), (u16*)(ws + W1BT), b1f, b1b, zxF, zxB);
    lstm_rec_k<<<64, 256, 0, stream>>>(
        zxF, zxB, (u16*)(ws + U1FT), (u16*)(ws + U1BT), maskw,
        (u16*)(ws + HBUF), (u16*)(ws + HBUF + 131072),
        &flgs[0], &flgs[128], out1, nullptr, 1);

    gemm_bias_k<<<dim3(16, 128, 2), 256, 0, stream>>>(
        out1, 1024, (u16*)(ws + W2FT), (u16*)(ws + W2BT), b2f, b2b, zxF, zxB);
    lstm_rec_k<<<64, 256, 0, stream>>>(
        zxF, zxB, (u16*)(ws + U2FT), (u16*)(ws + U2BT), maskw,
        (u16*)(ws + HBUF + 262144), (u16*)(ws + HBUF + 393216),
        &flgs[256], &flgs[384], nullptr, (float*)d_out, 2);
}